// Round 7
// baseline (171.479 us; speedup 1.0000x reference)
//
#include <hip/hip_runtime.h>

// LTAE2d tiny, folded: score[h,pix,l] = 0.5*( sum_g inv_g*(d_g[h][l] - mu_g*U[h][g])
//                                             + wb[h] + s0[h] + pterm[h][b][l] )
// k1a: stats PARTIALS in k2's proven-fast loop shape (480 blocks = (pixwin,l));
//      per g: s=Σx, q=Σx² over 8 ch -> ws scratch [l][g][pix]. Block 480 = precompute.
// k1r: reduce 30 l-partials -> inv, mu*inv in ws.
// k2 : scores (unchanged, proven ~10us).   k3: softmax over L=30.

#define EPSV 1e-5f

// ws float offsets
#define WS_U    0          // u[c][h]        128*16
#define WS_UU   2048       // U[g][h]        16*16
#define WS_P2   2304       // P2[b*30+l][h]  120*16
#define WS_FLAG 4224       // flag[b*30+l]   120
#define WS_QT   4352       // qt[h][m]       16*256
#define WS_WT   8448       // wt[h][c]       16*128
#define WS_INV  10496      // inv[g][pix]    16*16384
#define WS_MUI  272640     // mu*inv[g][pix] 16*16384
// partial scratch: PS[l][g][16384], PSQ likewise
#define PSF  1048576       // float offset (4 MB)
#define PSQ  8912896       // PSF + 30*16*16384

#define ACC4(S, Q, V) { (S).x += (V).x; (S).y += (V).y; (S).z += (V).z; (S).w += (V).w; \
                        (Q).x += (V).x*(V).x; (Q).y += (V).y*(V).y; (Q).z += (V).z*(V).z; (Q).w += (V).w*(V).w; }
#define FMA4(A, S, V) { (A).x += (S)*(V).x; (A).y += (S)*(V).y; (A).z += (S)*(V).z; (A).w += (S)*(V).w; }
#define NMA4(A, S, V) { (A).x -= (S)*(V).x; (A).y -= (S)*(V).y; (A).z -= (S)*(V).z; (A).w -= (S)*(V).w; }

// ---- k1a: stats partials (blocks 0..479, k2-shaped) + precompute (block 480) ----
__global__ void __launch_bounds__(256) k1a(const float* __restrict__ Q,
                                           const float* __restrict__ Wk,
                                           const float* __restrict__ conv_w,
                                           const float* __restrict__ gn_w,
                                           const float* __restrict__ conv_b,
                                           const float* __restrict__ gn_b,
                                           const float* __restrict__ bk,
                                           const int* __restrict__ bpos,
                                           const unsigned char* __restrict__ pmask,
                                           const float* __restrict__ x,
                                           float* __restrict__ ws) {
    int t = threadIdx.x;
    int bx = blockIdx.x;
    if (bx >= 480) {
        // ================= precompute block =================
        __shared__ float red[256];
        __shared__ float sc[16];
        __shared__ float qsv[256];
        __shared__ float rden[16];
        for (int i = t; i < 4096; i += 256) {
            int h = i >> 8, m = i & 255;
            float s = 0.f;
            #pragma unroll
            for (int d = 0; d < 4; ++d) s += Q[h*4+d] * Wk[(h*4+d)*256 + m];
            ws[WS_QT + h*256 + m] = s;
        }
        __syncthreads();
        for (int i = t; i < 2048; i += 256) {
            int h = i >> 7, c = i & 127;
            const float* qt = ws + WS_QT + h*256;
            float s = 0.f;
            #pragma unroll 32
            for (int m = 0; m < 256; ++m) s += qt[m] * conv_w[m*128 + c];
            ws[WS_WT + h*128 + c] = s;
            ws[WS_U  + c*16  + h] = s * gn_w[c];
        }
        __syncthreads();
        {
            int h = t >> 4, g2 = t & 15;
            float s = 0.f;
            #pragma unroll
            for (int cc = 0; cc < 8; ++cc) s += ws[WS_U + (g2*8+cc)*16 + h];
            ws[WS_UU + g2*16 + h] = s;
            float q = 0.f;
            #pragma unroll
            for (int r = 0; r < 16; ++r) q += ws[WS_QT + h*256 + r*16 + g2];
            qsv[h*16 + g2] = q;
        }
        {
            int h = t >> 4, p = t & 15;
            float s = 0.f;
            #pragma unroll
            for (int i = 0; i < 8; ++i) { int c = p*8+i; s += ws[WS_WT + h*128 + c] * gn_b[c]; }
            red[t] = s;
        }
        __syncthreads();
        if (t < 16) {
            float wb = 0.f;
            #pragma unroll
            for (int p = 0; p < 16; ++p) wb += red[t*16+p];
            sc[t] = wb;
        }
        __syncthreads();
        {
            int h = t >> 4, p = t & 15;
            float s = 0.f;
            #pragma unroll
            for (int i = 0; i < 16; ++i) { int m = p*16+i; s += ws[WS_QT + h*256 + m] * conv_b[m]; }
            red[t] = s;
        }
        __syncthreads();
        if (t < 16) {
            float s0 = 0.f;
            #pragma unroll
            for (int p = 0; p < 16; ++p) s0 += red[t*16+p];
            #pragma unroll
            for (int d = 0; d < 4; ++d) s0 += Q[t*4+d] * bk[t*4+d];
            sc[t] += s0;
            rden[t] = powf(1000.0f, -((float)(t >> 1)) * 0.125f);
        }
        if (t < 120) ws[WS_FLAG + t] = pmask[t] ? 1.f : 0.f;
        __syncthreads();
        for (int idx = t; idx < 1920; idx += 256) {
            int h = idx / 120, r = idx - h*120;     // r = b*30+l
            float pos = (float)bpos[r];
            float pt = 0.f;
            #pragma unroll
            for (int p = 0; p < 16; ++p) {
                float tab = pos * rden[p];
                float v = (p & 1) ? cosf(tab) : sinf(tab);
                pt += v * qsv[h*16 + p];
            }
            ws[WS_P2 + r*16 + h] = pt + sc[h];
        }
        return;
    }
    // ================= stats partials, k2-shaped =================
    int pb2 = bx / 30, l = bx - pb2*30;
    int pixbase = pb2 * 1024;            // block-uniform
    int b = pixbase >> 12;
    int pijb = pixbase & 4095;
    int bl = b*30 + l;
    int pij = pijb + t*4;
    int pix0 = pixbase + t*4;
    const float* xbase = x + (bl*128)*4096 + pij;
    float* psb = ws + PSF + (l*16)*16384 + pix0;
    #pragma unroll 2
    for (int g = 0; g < 16; ++g) {
        const float* xg = xbase + g*8*4096;
        float4 s = make_float4(0.f,0.f,0.f,0.f);
        float4 q = make_float4(0.f,0.f,0.f,0.f);
        #pragma unroll
        for (int cc = 0; cc < 8; ++cc) {
            float4 v = *(const float4*)(xg + cc*4096);
            ACC4(s, q, v);
        }
        *(float4*)(psb + g*16384)              = s;
        *(float4*)(psb + g*16384 + (PSQ-PSF))  = q;
    }
}

// ---- k1r: reduce 30 l-partials -> inv, mu*inv ----
__global__ void __launch_bounds__(256) k1r(float* __restrict__ ws) {
    int bx = blockIdx.x;               // 256 blocks: g = bx>>4, pw = bx&15
    int g = bx >> 4, pw = bx & 15;
    int pix = pw*1024 + threadIdx.x*4;
    const float* ps = ws + PSF + g*16384 + pix;
    float4 S = make_float4(0.f,0.f,0.f,0.f);
    float4 SS = make_float4(0.f,0.f,0.f,0.f);
    #pragma unroll 5
    for (int l = 0; l < 30; ++l) {
        float4 a = *(const float4*)(ps + l*16*16384);
        float4 b = *(const float4*)(ps + l*16*16384 + (PSQ-PSF));
        S.x += a.x; S.y += a.y; S.z += a.z; S.w += a.w;
        SS.x += b.x; SS.y += b.y; SS.z += b.z; SS.w += b.w;
    }
    float4 inv, mui;
    {
        float mu = S.x*(1.f/240.f); float va = SS.x*(1.f/240.f) - mu*mu;
        inv.x = rsqrtf(va + EPSV); mui.x = mu*inv.x;
        mu = S.y*(1.f/240.f); va = SS.y*(1.f/240.f) - mu*mu;
        inv.y = rsqrtf(va + EPSV); mui.y = mu*inv.y;
        mu = S.z*(1.f/240.f); va = SS.z*(1.f/240.f) - mu*mu;
        inv.z = rsqrtf(va + EPSV); mui.z = mu*inv.z;
        mu = S.w*(1.f/240.f); va = SS.w*(1.f/240.f) - mu*mu;
        inv.w = rsqrtf(va + EPSV); mui.w = mu*inv.w;
    }
    *(float4*)(ws + WS_INV + g*16384 + pix) = inv;
    *(float4*)(ws + WS_MUI + g*16384 + pix) = mui;
}

// ---- k2: raw scores, 4 pixels/thread (unchanged, proven fast) ----
__global__ void __launch_bounds__(256) k2(const float* __restrict__ x,
                                          const float* __restrict__ ws,
                                          float* __restrict__ out) {
    __shared__ float su[2048];   // u[c][h]
    __shared__ float sU[256];    // U[g][h]
    __shared__ float sP2[16];
    __shared__ float sflag;
    int t = threadIdx.x;
    int bx = blockIdx.x;                 // 480 blocks: pb2 = bx/30, l = bx%30
    int pb2 = bx / 30, l = bx - pb2*30;
    int pixbase = pb2 * 1024;            // block-uniform
    int b = pixbase >> 12;
    int pijb = pixbase & 4095;
    int bl = b*30 + l;
    int pij = pijb + t*4;
    int pix0 = pixbase + t*4;

    for (int i = t; i < 512; i += 256)
        *(float4*)(su + i*4) = *(const float4*)(ws + WS_U + i*4);
    sU[t] = ws[WS_UU + t];
    if (t < 16) sP2[t] = ws[WS_P2 + bl*16 + t];
    if (t == 0) sflag = ws[WS_FLAG + bl];
    __syncthreads();

    float4 acc[16];
    #pragma unroll
    for (int h = 0; h < 16; ++h) acc[h] = make_float4(0.f, 0.f, 0.f, 0.f);
    const float* xbase = x + (bl*128)*4096 + pij;
    #pragma unroll 2
    for (int g = 0; g < 16; ++g) {
        float4 inv = *(const float4*)(ws + WS_INV + g*16384 + pix0);
        float4 mui = *(const float4*)(ws + WS_MUI + g*16384 + pix0);
        const float* us = su + g*128;
        #pragma unroll
        for (int q = 0; q < 4; ++q) {
            float4 Ug = *(const float4*)(sU + g*16 + q*4);
            NMA4(acc[q*4+0], Ug.x, mui); NMA4(acc[q*4+1], Ug.y, mui);
            NMA4(acc[q*4+2], Ug.z, mui); NMA4(acc[q*4+3], Ug.w, mui);
        }
        const float* xg = xbase + g*8*4096;
        #pragma unroll
        for (int cc = 0; cc < 8; ++cc) {
            float4 v = *(const float4*)(xg + cc*4096);
            float4 xs;
            xs.x = v.x*inv.x; xs.y = v.y*inv.y; xs.z = v.z*inv.z; xs.w = v.w*inv.w;
            #pragma unroll
            for (int q = 0; q < 4; ++q) {
                float4 uq = *(const float4*)(us + cc*16 + q*4);  // ds_read_b128 broadcast
                FMA4(acc[q*4+0], uq.x, xs); FMA4(acc[q*4+1], uq.y, xs);
                FMA4(acc[q*4+2], uq.z, xs); FMA4(acc[q*4+3], uq.w, xs);
            }
        }
    }
    bool msk = (sflag != 0.f);
    #pragma unroll
    for (int h = 0; h < 16; ++h) {
        float p2 = sP2[h];
        float4 sv;
        sv.x = 0.5f*(acc[h].x + p2); sv.y = 0.5f*(acc[h].y + p2);
        sv.z = 0.5f*(acc[h].z + p2); sv.w = 0.5f*(acc[h].w + p2);
        if (msk) sv = make_float4(-1000.f, -1000.f, -1000.f, -1000.f);
        *(float4*)(out + ((h*4 + b)*30 + l)*4096 + pij) = sv;
    }
}

// ---- k3: softmax over l, 2 pixels/thread ----
__global__ void __launch_bounds__(256) k3(float* __restrict__ out) {
    int idx = blockIdx.x*256 + threadIdx.x;   // 131072 threads
    int hb = idx >> 11;                       // 64 (h*4+b) slabs
    int pij = (idx & 2047)*2;
    float* p = out + hb*30*4096 + pij;
    float2 v[30];
    float m0 = -1e30f, m1 = -1e30f;
    #pragma unroll
    for (int l = 0; l < 30; ++l) {
        v[l] = *(const float2*)(p + l*4096);
        m0 = fmaxf(m0, v[l].x); m1 = fmaxf(m1, v[l].y);
    }
    float s0 = 0.f, s1 = 0.f;
    #pragma unroll
    for (int l = 0; l < 30; ++l) {
        v[l].x = __expf(v[l].x - m0); s0 += v[l].x;
        v[l].y = __expf(v[l].y - m1); s1 += v[l].y;
    }
    float r0 = 1.f/s0, r1 = 1.f/s1;
    #pragma unroll
    for (int l = 0; l < 30; ++l) {
        *(float2*)(p + l*4096) = make_float2(v[l].x*r0, v[l].y*r1);
    }
}

extern "C" void kernel_launch(void* const* d_in, const int* in_sizes, int n_in,
                              void* d_out, int out_size, void* d_ws, size_t ws_size,
                              hipStream_t stream) {
    const float* x      = (const float*)d_in[0];
    const float* gn_w   = (const float*)d_in[1];
    const float* gn_b   = (const float*)d_in[2];
    const float* conv_w = (const float*)d_in[3];
    const float* conv_b = (const float*)d_in[4];
    const float* Q      = (const float*)d_in[5];
    const float* Wk     = (const float*)d_in[6];
    const float* bk     = (const float*)d_in[7];
    const int*   bpos   = (const int*)d_in[8];
    const unsigned char* pmask = (const unsigned char*)d_in[9];
    float* ws  = (float*)d_ws;
    float* out = (float*)d_out;

    hipLaunchKernelGGL(k1a, dim3(481), dim3(256), 0, stream,
                       Q, Wk, conv_w, gn_w, conv_b, gn_b, bk, bpos, pmask, x, ws);
    hipLaunchKernelGGL(k1r, dim3(256), dim3(256), 0, stream, ws);
    hipLaunchKernelGGL(k2,  dim3(480), dim3(256), 0, stream, x, ws, out);
    hipLaunchKernelGGL(k3,  dim3(512), dim3(256), 0, stream, out);
}

// Round 8
// 171.307 us; speedup vs baseline: 1.0010x; 1.0010x over previous
//
#include <hip/hip_runtime.h>

// LTAE2d tiny, folded: score[h,pix,l] = 0.5*( sum_g inv_g*(d_g[h][l] - mu_g*U[h][g])
//                                             + wb[h] + s0[h] + pterm[h][b][l] )
// k1s: per-CHANNEL stats partials (30 independent float4 loads/thread, 2048 blocks)
//      -> PS/PSQ[b][c][pix] in ws. Block 2048 = small precompute.
// k1r: reduce 8 channels/group -> inv, mu*inv.
// k2 : scores (r7 version, known-correct).  k3: softmax over L=30.

#define EPSV 1e-5f

// ws float offsets
#define WS_U    0          // u[c][h]        128*16
#define WS_UU   2048       // U[g][h]        16*16
#define WS_P2   2304       // P2[b*30+l][h]  120*16
#define WS_FLAG 4224       // flag[b*30+l]   120
#define WS_QT   4352       // qt[h][m]       16*256
#define WS_WT   8448       // wt[h][c]       16*128
#define WS_INV  10496      // inv[g][pix]    16*16384
#define WS_MUI  272640     // mu*inv[g][pix] 16*16384
// per-channel partials: PS[b][c][4096], PSQ likewise
#define PSF  1048576       // float offset (4 MB into ws)
#define PSQD 2097152       // PSQ = PSF + 4*128*4096

#define ADD4(A, V)  { (A).x += (V).x; (A).y += (V).y; (A).z += (V).z; (A).w += (V).w; }
#define ADDSQ4(A,V) { (A).x += (V).x*(V).x; (A).y += (V).y*(V).y; (A).z += (V).z*(V).z; (A).w += (V).w*(V).w; }
#define FMA4(A, S, V) { (A).x += (S)*(V).x; (A).y += (S)*(V).y; (A).z += (S)*(V).z; (A).w += (S)*(V).w; }
#define NMA4(A, S, V) { (A).x -= (S)*(V).x; (A).y -= (S)*(V).y; (A).z -= (S)*(V).z; (A).w -= (S)*(V).w; }

// ---- k1s: per-channel stats partials (blocks 0..2047) + precompute (block 2048) ----
__global__ void __launch_bounds__(256) k1s(const float* __restrict__ Q,
                                           const float* __restrict__ Wk,
                                           const float* __restrict__ conv_w,
                                           const float* __restrict__ gn_w,
                                           const float* __restrict__ conv_b,
                                           const float* __restrict__ gn_b,
                                           const float* __restrict__ bk,
                                           const int* __restrict__ bpos,
                                           const unsigned char* __restrict__ pmask,
                                           const float* __restrict__ x,
                                           float* __restrict__ ws) {
    int t = threadIdx.x;
    int bx = blockIdx.x;
    if (bx >= 2048) {
        // ================= precompute block =================
        __shared__ float red[256];
        __shared__ float sc[16];
        __shared__ float qsv[256];
        __shared__ float rden[16];
        for (int i = t; i < 4096; i += 256) {
            int h = i >> 8, m = i & 255;
            float s = 0.f;
            #pragma unroll
            for (int d = 0; d < 4; ++d) s += Q[h*4+d] * Wk[(h*4+d)*256 + m];
            ws[WS_QT + h*256 + m] = s;
        }
        __syncthreads();
        for (int i = t; i < 2048; i += 256) {
            int h = i >> 7, c = i & 127;
            const float* qt = ws + WS_QT + h*256;
            float s = 0.f;
            #pragma unroll 32
            for (int m = 0; m < 256; ++m) s += qt[m] * conv_w[m*128 + c];
            ws[WS_WT + h*128 + c] = s;
            ws[WS_U  + c*16  + h] = s * gn_w[c];
        }
        __syncthreads();
        {
            int h = t >> 4, g2 = t & 15;
            float s = 0.f;
            #pragma unroll
            for (int cc = 0; cc < 8; ++cc) s += ws[WS_U + (g2*8+cc)*16 + h];
            ws[WS_UU + g2*16 + h] = s;
            float q = 0.f;
            #pragma unroll
            for (int r = 0; r < 16; ++r) q += ws[WS_QT + h*256 + r*16 + g2];
            qsv[h*16 + g2] = q;
        }
        {
            int h = t >> 4, p = t & 15;
            float s = 0.f;
            #pragma unroll
            for (int i = 0; i < 8; ++i) { int c = p*8+i; s += ws[WS_WT + h*128 + c] * gn_b[c]; }
            red[t] = s;
        }
        __syncthreads();
        if (t < 16) {
            float wb = 0.f;
            #pragma unroll
            for (int p = 0; p < 16; ++p) wb += red[t*16+p];
            sc[t] = wb;
        }
        __syncthreads();
        {
            int h = t >> 4, p = t & 15;
            float s = 0.f;
            #pragma unroll
            for (int i = 0; i < 16; ++i) { int m = p*16+i; s += ws[WS_QT + h*256 + m] * conv_b[m]; }
            red[t] = s;
        }
        __syncthreads();
        if (t < 16) {
            float s0 = 0.f;
            #pragma unroll
            for (int p = 0; p < 16; ++p) s0 += red[t*16+p];
            #pragma unroll
            for (int d = 0; d < 4; ++d) s0 += Q[t*4+d] * bk[t*4+d];
            sc[t] += s0;
            rden[t] = powf(1000.0f, -((float)(t >> 1)) * 0.125f);
        }
        if (t < 120) ws[WS_FLAG + t] = pmask[t] ? 1.f : 0.f;
        __syncthreads();
        for (int idx = t; idx < 1920; idx += 256) {
            int h = idx / 120, r = idx - h*120;     // r = b*30+l
            float pos = (float)bpos[r];
            float pt = 0.f;
            #pragma unroll
            for (int p = 0; p < 16; ++p) {
                float tab = pos * rden[p];
                float v = (p & 1) ? cosf(tab) : sinf(tab);
                pt += v * qsv[h*16 + p];
            }
            ws[WS_P2 + r*16 + h] = pt + sc[h];
        }
        return;
    }
    // ---- per-channel partials: 30 INDEPENDENT float4 loads, no cross-channel chain ----
    int b = bx >> 9;            // 0..3
    int rem = bx & 511;
    int c = rem >> 2;           // 0..127
    int w = rem & 3;            // 0..3 (1024-px window)
    int pij = w*1024 + t*4;
    const float* xp = x + ((b*30)*128 + c)*4096 + pij;
    float4 s = make_float4(0.f,0.f,0.f,0.f);
    float4 q = make_float4(0.f,0.f,0.f,0.f);
    #pragma unroll
    for (int l = 0; l < 30; ++l) {
        float4 v = *(const float4*)(xp + l*524288);   // l-stride = 128*4096
        ADD4(s, v); ADDSQ4(q, v);
    }
    float* ps = ws + PSF + (b*128 + c)*4096 + pij;
    *(float4*)(ps)        = s;
    *(float4*)(ps + PSQD) = q;
}

// ---- k1r: reduce 8 channels per group -> inv, mu*inv ----
__global__ void __launch_bounds__(256) k1r(float* __restrict__ ws) {
    int bx = blockIdx.x;               // 256 blocks: g = bx>>4, w = bx&15
    int g = bx >> 4, w = bx & 15;
    int p0 = w*1024 + threadIdx.x*4;   // 0..16383
    int b = p0 >> 12, pij = p0 & 4095;
    const float* base = ws + PSF + (b*128 + g*8)*4096 + pij;
    float4 S = make_float4(0.f,0.f,0.f,0.f);
    float4 SS = make_float4(0.f,0.f,0.f,0.f);
    #pragma unroll
    for (int cc = 0; cc < 8; ++cc) {
        float4 a = *(const float4*)(base + cc*4096);
        float4 bq = *(const float4*)(base + cc*4096 + PSQD);
        ADD4(S, a); ADD4(SS, bq);
    }
    float4 inv, mui;
    {
        float mu = S.x*(1.f/240.f); float va = SS.x*(1.f/240.f) - mu*mu;
        inv.x = rsqrtf(va + EPSV); mui.x = mu*inv.x;
        mu = S.y*(1.f/240.f); va = SS.y*(1.f/240.f) - mu*mu;
        inv.y = rsqrtf(va + EPSV); mui.y = mu*inv.y;
        mu = S.z*(1.f/240.f); va = SS.z*(1.f/240.f) - mu*mu;
        inv.z = rsqrtf(va + EPSV); mui.z = mu*inv.z;
        mu = S.w*(1.f/240.f); va = SS.w*(1.f/240.f) - mu*mu;
        inv.w = rsqrtf(va + EPSV); mui.w = mu*inv.w;
    }
    *(float4*)(ws + WS_INV + g*16384 + p0) = inv;
    *(float4*)(ws + WS_MUI + g*16384 + p0) = mui;
}

// ---- k2: raw scores, 4 pixels/thread (unchanged, known-correct) ----
__global__ void __launch_bounds__(256) k2(const float* __restrict__ x,
                                          const float* __restrict__ ws,
                                          float* __restrict__ out) {
    __shared__ float su[2048];   // u[c][h]
    __shared__ float sU[256];    // U[g][h]
    __shared__ float sP2[16];
    __shared__ float sflag;
    int t = threadIdx.x;
    int bx = blockIdx.x;                 // 480 blocks: pb2 = bx/30, l = bx%30
    int pb2 = bx / 30, l = bx - pb2*30;
    int pixbase = pb2 * 1024;            // block-uniform
    int b = pixbase >> 12;
    int pijb = pixbase & 4095;
    int bl = b*30 + l;
    int pij = pijb + t*4;
    int pix0 = pixbase + t*4;

    for (int i = t; i < 512; i += 256)
        *(float4*)(su + i*4) = *(const float4*)(ws + WS_U + i*4);
    sU[t] = ws[WS_UU + t];
    if (t < 16) sP2[t] = ws[WS_P2 + bl*16 + t];
    if (t == 0) sflag = ws[WS_FLAG + bl];
    __syncthreads();

    float4 acc[16];
    #pragma unroll
    for (int h = 0; h < 16; ++h) acc[h] = make_float4(0.f, 0.f, 0.f, 0.f);
    const float* xbase = x + (bl*128)*4096 + pij;
    #pragma unroll 2
    for (int g = 0; g < 16; ++g) {
        float4 inv = *(const float4*)(ws + WS_INV + g*16384 + pix0);
        float4 mui = *(const float4*)(ws + WS_MUI + g*16384 + pix0);
        const float* us = su + g*128;
        #pragma unroll
        for (int q = 0; q < 4; ++q) {
            float4 Ug = *(const float4*)(sU + g*16 + q*4);
            NMA4(acc[q*4+0], Ug.x, mui); NMA4(acc[q*4+1], Ug.y, mui);
            NMA4(acc[q*4+2], Ug.z, mui); NMA4(acc[q*4+3], Ug.w, mui);
        }
        const float* xg = xbase + g*8*4096;
        #pragma unroll
        for (int cc = 0; cc < 8; ++cc) {
            float4 v = *(const float4*)(xg + cc*4096);
            float4 xs;
            xs.x = v.x*inv.x; xs.y = v.y*inv.y; xs.z = v.z*inv.z; xs.w = v.w*inv.w;
            #pragma unroll
            for (int q = 0; q < 4; ++q) {
                float4 uq = *(const float4*)(us + cc*16 + q*4);  // ds_read_b128 broadcast
                FMA4(acc[q*4+0], uq.x, xs); FMA4(acc[q*4+1], uq.y, xs);
                FMA4(acc[q*4+2], uq.z, xs); FMA4(acc[q*4+3], uq.w, xs);
            }
        }
    }
    bool msk = (sflag != 0.f);
    #pragma unroll
    for (int h = 0; h < 16; ++h) {
        float p2 = sP2[h];
        float4 sv;
        sv.x = 0.5f*(acc[h].x + p2); sv.y = 0.5f*(acc[h].y + p2);
        sv.z = 0.5f*(acc[h].z + p2); sv.w = 0.5f*(acc[h].w + p2);
        if (msk) sv = make_float4(-1000.f, -1000.f, -1000.f, -1000.f);
        *(float4*)(out + ((h*4 + b)*30 + l)*4096 + pij) = sv;
    }
}

// ---- k3: softmax over l, 2 pixels/thread ----
__global__ void __launch_bounds__(256) k3(float* __restrict__ out) {
    int idx = blockIdx.x*256 + threadIdx.x;   // 131072 threads
    int hb = idx >> 11;                       // 64 (h*4+b) slabs
    int pij = (idx & 2047)*2;
    float* p = out + hb*30*4096 + pij;
    float2 v[30];
    float m0 = -1e30f, m1 = -1e30f;
    #pragma unroll
    for (int l = 0; l < 30; ++l) {
        v[l] = *(const float2*)(p + l*4096);
        m0 = fmaxf(m0, v[l].x); m1 = fmaxf(m1, v[l].y);
    }
    float s0 = 0.f, s1 = 0.f;
    #pragma unroll
    for (int l = 0; l < 30; ++l) {
        v[l].x = __expf(v[l].x - m0); s0 += v[l].x;
        v[l].y = __expf(v[l].y - m1); s1 += v[l].y;
    }
    float r0 = 1.f/s0, r1 = 1.f/s1;
    #pragma unroll
    for (int l = 0; l < 30; ++l) {
        *(float2*)(p + l*4096) = make_float2(v[l].x*r0, v[l].y*r1);
    }
}

extern "C" void kernel_launch(void* const* d_in, const int* in_sizes, int n_in,
                              void* d_out, int out_size, void* d_ws, size_t ws_size,
                              hipStream_t stream) {
    const float* x      = (const float*)d_in[0];
    const float* gn_w   = (const float*)d_in[1];
    const float* gn_b   = (const float*)d_in[2];
    const float* conv_w = (const float*)d_in[3];
    const float* conv_b = (const float*)d_in[4];
    const float* Q      = (const float*)d_in[5];
    const float* Wk     = (const float*)d_in[6];
    const float* bk     = (const float*)d_in[7];
    const int*   bpos   = (const int*)d_in[8];
    const unsigned char* pmask = (const unsigned char*)d_in[9];
    float* ws  = (float*)d_ws;
    float* out = (float*)d_out;

    hipLaunchKernelGGL(k1s, dim3(2049), dim3(256), 0, stream,
                       Q, Wk, conv_w, gn_w, conv_b, gn_b, bk, bpos, pmask, x, ws);
    hipLaunchKernelGGL(k1r, dim3(256),  dim3(256), 0, stream, ws);
    hipLaunchKernelGGL(k2,  dim3(480),  dim3(256), 0, stream, x, ws, out);
    hipLaunchKernelGGL(k3,  dim3(512),  dim3(256), 0, stream, out);
}

// Round 9
// 168.436 us; speedup vs baseline: 1.0181x; 1.0170x over previous
//
#include <hip/hip_runtime.h>

// LTAE2d tiny, folded: score[h,pix,l] = 0.5*( sum_g inv_g*(d_g[h][l] - mu_g*U[h][g])
//                                             + wb[h] + s0[h] + pterm[h][b][l] )
// k1s: per-CHANNEL stats partials, FORWARD sweep of x -> PS/PSQ[b][c][pix] (16 MB ws).
//      Block 2048 = small precompute.
// k1r: reduce 8 channels/group -> inv, mu*inv.
// k2 : scores, REVERSE block order (boustrophedon: starts where k1s ended, L3-hot).
// k3 : softmax over L=30.

#define EPSV 1e-5f

// ws float offsets
#define WS_U    0          // u[c][h]        128*16
#define WS_UU   2048       // U[g][h]        16*16
#define WS_P2   2304       // P2[b*30+l][h]  120*16
#define WS_FLAG 4224       // flag[b*30+l]   120
#define WS_QT   4352       // qt[h][m]       16*256
#define WS_WT   8448       // wt[h][c]       16*128
#define WS_INV  10496      // inv[g][pix]    16*16384
#define WS_MUI  272640     // mu*inv[g][pix] 16*16384
// per-channel partials: PS[b][c][4096], PSQ likewise
#define PSF  1048576       // float offset (4 MB into ws)
#define PSQD 2097152       // PSQ = PSF + 4*128*4096

#define ADD4(A, V)  { (A).x += (V).x; (A).y += (V).y; (A).z += (V).z; (A).w += (V).w; }
#define ADDSQ4(A,V) { (A).x += (V).x*(V).x; (A).y += (V).y*(V).y; (A).z += (V).z*(V).z; (A).w += (V).w*(V).w; }
#define FMA4(A, S, V) { (A).x += (S)*(V).x; (A).y += (S)*(V).y; (A).z += (S)*(V).z; (A).w += (S)*(V).w; }
#define NMA4(A, S, V) { (A).x -= (S)*(V).x; (A).y -= (S)*(V).y; (A).z -= (S)*(V).z; (A).w -= (S)*(V).w; }

// ---- k1s: per-channel stats partials (blocks 0..2047) + precompute (block 2048) ----
__global__ void __launch_bounds__(256, 2) k1s(const float* __restrict__ Q,
                                              const float* __restrict__ Wk,
                                              const float* __restrict__ conv_w,
                                              const float* __restrict__ gn_w,
                                              const float* __restrict__ conv_b,
                                              const float* __restrict__ gn_b,
                                              const float* __restrict__ bk,
                                              const int* __restrict__ bpos,
                                              const unsigned char* __restrict__ pmask,
                                              const float* __restrict__ x,
                                              float* __restrict__ ws) {
    int t = threadIdx.x;
    int bx = blockIdx.x;
    if (bx >= 2048) {
        // ================= precompute block =================
        __shared__ float red[256];
        __shared__ float sc[16];
        __shared__ float qsv[256];
        __shared__ float rden[16];
        for (int i = t; i < 4096; i += 256) {
            int h = i >> 8, m = i & 255;
            float s = 0.f;
            #pragma unroll
            for (int d = 0; d < 4; ++d) s += Q[h*4+d] * Wk[(h*4+d)*256 + m];
            ws[WS_QT + h*256 + m] = s;
        }
        __syncthreads();
        for (int i = t; i < 2048; i += 256) {
            int h = i >> 7, c = i & 127;
            const float* qt = ws + WS_QT + h*256;
            float s = 0.f;
            #pragma unroll 32
            for (int m = 0; m < 256; ++m) s += qt[m] * conv_w[m*128 + c];
            ws[WS_WT + h*128 + c] = s;
            ws[WS_U  + c*16  + h] = s * gn_w[c];
        }
        __syncthreads();
        {
            int h = t >> 4, g2 = t & 15;
            float s = 0.f;
            #pragma unroll
            for (int cc = 0; cc < 8; ++cc) s += ws[WS_U + (g2*8+cc)*16 + h];
            ws[WS_UU + g2*16 + h] = s;
            float q = 0.f;
            #pragma unroll
            for (int r = 0; r < 16; ++r) q += ws[WS_QT + h*256 + r*16 + g2];
            qsv[h*16 + g2] = q;
        }
        {
            int h = t >> 4, p = t & 15;
            float s = 0.f;
            #pragma unroll
            for (int i = 0; i < 8; ++i) { int c = p*8+i; s += ws[WS_WT + h*128 + c] * gn_b[c]; }
            red[t] = s;
        }
        __syncthreads();
        if (t < 16) {
            float wb = 0.f;
            #pragma unroll
            for (int p = 0; p < 16; ++p) wb += red[t*16+p];
            sc[t] = wb;
        }
        __syncthreads();
        {
            int h = t >> 4, p = t & 15;
            float s = 0.f;
            #pragma unroll
            for (int i = 0; i < 16; ++i) { int m = p*16+i; s += ws[WS_QT + h*256 + m] * conv_b[m]; }
            red[t] = s;
        }
        __syncthreads();
        if (t < 16) {
            float s0 = 0.f;
            #pragma unroll
            for (int p = 0; p < 16; ++p) s0 += red[t*16+p];
            #pragma unroll
            for (int d = 0; d < 4; ++d) s0 += Q[t*4+d] * bk[t*4+d];
            sc[t] += s0;
            rden[t] = powf(1000.0f, -((float)(t >> 1)) * 0.125f);
        }
        if (t < 120) ws[WS_FLAG + t] = pmask[t] ? 1.f : 0.f;
        __syncthreads();
        for (int idx = t; idx < 1920; idx += 256) {
            int h = idx / 120, r = idx - h*120;     // r = b*30+l
            float pos = (float)bpos[r];
            float pt = 0.f;
            #pragma unroll
            for (int p = 0; p < 16; ++p) {
                float tab = pos * rden[p];
                float v = (p & 1) ? cosf(tab) : sinf(tab);
                pt += v * qsv[h*16 + p];
            }
            ws[WS_P2 + r*16 + h] = pt + sc[h];
        }
        return;
    }
    // ---- per-channel partials: 30 independent loads, clustered via static array ----
    int b = bx >> 9;            // 0..3
    int rem = bx & 511;
    int c = rem >> 2;           // 0..127
    int w = rem & 3;            // 0..3 (1024-px window)
    int pij = w*1024 + t*4;
    const float* xp = x + ((b*30)*128 + c)*4096 + pij;
    float4 vv[30];
    #pragma unroll
    for (int l = 0; l < 30; ++l)
        vv[l] = *(const float4*)(xp + l*524288);   // l-stride = 128*4096
    float4 s = make_float4(0.f,0.f,0.f,0.f);
    float4 q = make_float4(0.f,0.f,0.f,0.f);
    #pragma unroll
    for (int l = 0; l < 30; ++l) { ADD4(s, vv[l]); ADDSQ4(q, vv[l]); }
    float* ps = ws + PSF + (b*128 + c)*4096 + pij;
    *(float4*)(ps)        = s;
    *(float4*)(ps + PSQD) = q;
}

// ---- k1r: reduce 8 channels per group -> inv, mu*inv ----
__global__ void __launch_bounds__(256) k1r(float* __restrict__ ws) {
    int bx = blockIdx.x;               // 256 blocks: g = bx>>4, w = bx&15
    int g = bx >> 4, w = bx & 15;
    int p0 = w*1024 + threadIdx.x*4;   // 0..16383
    int b = p0 >> 12, pij = p0 & 4095;
    const float* base = ws + PSF + (b*128 + g*8)*4096 + pij;
    float4 S = make_float4(0.f,0.f,0.f,0.f);
    float4 SS = make_float4(0.f,0.f,0.f,0.f);
    #pragma unroll
    for (int cc = 0; cc < 8; ++cc) {
        float4 a = *(const float4*)(base + cc*4096);
        float4 bq = *(const float4*)(base + cc*4096 + PSQD);
        ADD4(S, a); ADD4(SS, bq);
    }
    float4 inv, mui;
    {
        float mu = S.x*(1.f/240.f); float va = SS.x*(1.f/240.f) - mu*mu;
        inv.x = rsqrtf(va + EPSV); mui.x = mu*inv.x;
        mu = S.y*(1.f/240.f); va = SS.y*(1.f/240.f) - mu*mu;
        inv.y = rsqrtf(va + EPSV); mui.y = mu*inv.y;
        mu = S.z*(1.f/240.f); va = SS.z*(1.f/240.f) - mu*mu;
        inv.z = rsqrtf(va + EPSV); mui.z = mu*inv.z;
        mu = S.w*(1.f/240.f); va = SS.w*(1.f/240.f) - mu*mu;
        inv.w = rsqrtf(va + EPSV); mui.w = mu*inv.w;
    }
    *(float4*)(ws + WS_INV + g*16384 + p0) = inv;
    *(float4*)(ws + WS_MUI + g*16384 + p0) = mui;
}

// ---- k2: raw scores, REVERSE block order (reads x back-to-front vs k1s) ----
__global__ void __launch_bounds__(256) k2(const float* __restrict__ x,
                                          const float* __restrict__ ws,
                                          float* __restrict__ out) {
    __shared__ float su[2048];   // u[c][h]
    __shared__ float sU[256];    // U[g][h]
    __shared__ float sP2[16];
    __shared__ float sflag;
    int t = threadIdx.x;
    int bx = 479 - (int)blockIdx.x;      // boustrophedon: start at k1s's hot tail
    int pb2 = bx / 30, l = bx - pb2*30;
    int pixbase = pb2 * 1024;            // block-uniform
    int b = pixbase >> 12;
    int pijb = pixbase & 4095;
    int bl = b*30 + l;
    int pij = pijb + t*4;
    int pix0 = pixbase + t*4;

    for (int i = t; i < 512; i += 256)
        *(float4*)(su + i*4) = *(const float4*)(ws + WS_U + i*4);
    sU[t] = ws[WS_UU + t];
    if (t < 16) sP2[t] = ws[WS_P2 + bl*16 + t];
    if (t == 0) sflag = ws[WS_FLAG + bl];
    __syncthreads();

    float4 acc[16];
    #pragma unroll
    for (int h = 0; h < 16; ++h) acc[h] = make_float4(0.f, 0.f, 0.f, 0.f);
    const float* xbase = x + (bl*128)*4096 + pij;
    #pragma unroll 2
    for (int g = 0; g < 16; ++g) {
        float4 inv = *(const float4*)(ws + WS_INV + g*16384 + pix0);
        float4 mui = *(const float4*)(ws + WS_MUI + g*16384 + pix0);
        const float* us = su + g*128;
        #pragma unroll
        for (int q = 0; q < 4; ++q) {
            float4 Ug = *(const float4*)(sU + g*16 + q*4);
            NMA4(acc[q*4+0], Ug.x, mui); NMA4(acc[q*4+1], Ug.y, mui);
            NMA4(acc[q*4+2], Ug.z, mui); NMA4(acc[q*4+3], Ug.w, mui);
        }
        const float* xg = xbase + g*8*4096;
        #pragma unroll
        for (int cc = 0; cc < 8; ++cc) {
            float4 v = *(const float4*)(xg + cc*4096);
            float4 xs;
            xs.x = v.x*inv.x; xs.y = v.y*inv.y; xs.z = v.z*inv.z; xs.w = v.w*inv.w;
            #pragma unroll
            for (int q = 0; q < 4; ++q) {
                float4 uq = *(const float4*)(us + cc*16 + q*4);  // ds_read_b128 broadcast
                FMA4(acc[q*4+0], uq.x, xs); FMA4(acc[q*4+1], uq.y, xs);
                FMA4(acc[q*4+2], uq.z, xs); FMA4(acc[q*4+3], uq.w, xs);
            }
        }
    }
    bool msk = (sflag != 0.f);
    #pragma unroll
    for (int h = 0; h < 16; ++h) {
        float p2 = sP2[h];
        float4 sv;
        sv.x = 0.5f*(acc[h].x + p2); sv.y = 0.5f*(acc[h].y + p2);
        sv.z = 0.5f*(acc[h].z + p2); sv.w = 0.5f*(acc[h].w + p2);
        if (msk) sv = make_float4(-1000.f, -1000.f, -1000.f, -1000.f);
        *(float4*)(out + ((h*4 + b)*30 + l)*4096 + pij) = sv;
    }
}

// ---- k3: softmax over l, 2 pixels/thread ----
__global__ void __launch_bounds__(256) k3(float* __restrict__ out) {
    int idx = blockIdx.x*256 + threadIdx.x;   // 131072 threads
    int hb = idx >> 11;                       // 64 (h*4+b) slabs
    int pij = (idx & 2047)*2;
    float* p = out + hb*30*4096 + pij;
    float2 v[30];
    float m0 = -1e30f, m1 = -1e30f;
    #pragma unroll
    for (int l = 0; l < 30; ++l) {
        v[l] = *(const float2*)(p + l*4096);
        m0 = fmaxf(m0, v[l].x); m1 = fmaxf(m1, v[l].y);
    }
    float s0 = 0.f, s1 = 0.f;
    #pragma unroll
    for (int l = 0; l < 30; ++l) {
        v[l].x = __expf(v[l].x - m0); s0 += v[l].x;
        v[l].y = __expf(v[l].y - m1); s1 += v[l].y;
    }
    float r0 = 1.f/s0, r1 = 1.f/s1;
    #pragma unroll
    for (int l = 0; l < 30; ++l) {
        *(float2*)(p + l*4096) = make_float2(v[l].x*r0, v[l].y*r1);
    }
}

extern "C" void kernel_launch(void* const* d_in, const int* in_sizes, int n_in,
                              void* d_out, int out_size, void* d_ws, size_t ws_size,
                              hipStream_t stream) {
    const float* x      = (const float*)d_in[0];
    const float* gn_w   = (const float*)d_in[1];
    const float* gn_b   = (const float*)d_in[2];
    const float* conv_w = (const float*)d_in[3];
    const float* conv_b = (const float*)d_in[4];
    const float* Q      = (const float*)d_in[5];
    const float* Wk     = (const float*)d_in[6];
    const float* bk     = (const float*)d_in[7];
    const int*   bpos   = (const int*)d_in[8];
    const unsigned char* pmask = (const unsigned char*)d_in[9];
    float* ws  = (float*)d_ws;
    float* out = (float*)d_out;

    hipLaunchKernelGGL(k1s, dim3(2049), dim3(256), 0, stream,
                       Q, Wk, conv_w, gn_w, conv_b, gn_b, bk, bpos, pmask, x, ws);
    hipLaunchKernelGGL(k1r, dim3(256),  dim3(256), 0, stream, ws);
    hipLaunchKernelGGL(k2,  dim3(480),  dim3(256), 0, stream, x, ws, out);
    hipLaunchKernelGGL(k3,  dim3(512),  dim3(256), 0, stream, out);
}

// Round 10
// 145.541 us; speedup vs baseline: 1.1782x; 1.1573x over previous
//
#include <hip/hip_runtime.h>

// LTAE2d tiny, folded: score[h,pix,l] = 0.5*( sum_g inv_g*(d_g[h][l] - mu_g*U[h][g])
//                                             + wb[h] + s0[h] + pterm[h][b][l] )
// Best-measured config (round 3, 156.0 us), restored:
// k0: small precompute, 1 block x 1024 (parallel-reduced wb/s0).
// k1: GN stats, 512 blocks, float2, inv/mui straight to ws (no partials).
// k2: scores, 480 blocks, 4 px/thread, b128 u-broadcast, g-loop unroll 1.
// k3: softmax over L=30, 256 blocks, float4.

#define EPSV 1e-5f

// ws float offsets
#define WS_U    0          // u[c][h]        128*16
#define WS_UU   2048       // U[g][h]        16*16
#define WS_P2   2304       // P2[b*30+l][h]  120*16
#define WS_FLAG 4224       // flag[b*30+l]   120
#define WS_QT   4352       // qt[h][m]       16*256
#define WS_WT   8448       // wt[h][c]       16*128
#define WS_INV  10496      // inv[g][pix]    16*16384
#define WS_MUI  272640     // mu*inv[g][pix] 16*16384

#define FMA4(A, S, V) { (A).x += (S)*(V).x; (A).y += (S)*(V).y; (A).z += (S)*(V).z; (A).w += (S)*(V).w; }
#define NMA4(A, S, V) { (A).x -= (S)*(V).x; (A).y -= (S)*(V).y; (A).z -= (S)*(V).z; (A).w -= (S)*(V).w; }

// ---- k0: all small precompute, one block of 1024 ----
__global__ void __launch_bounds__(1024) k0(const float* __restrict__ Q,
                                           const float* __restrict__ Wk,
                                           const float* __restrict__ conv_w,
                                           const float* __restrict__ gn_w,
                                           const float* __restrict__ conv_b,
                                           const float* __restrict__ gn_b,
                                           const float* __restrict__ bk,
                                           const int* __restrict__ bpos,
                                           const unsigned char* __restrict__ pmask,
                                           float* __restrict__ ws) {
    int t = threadIdx.x;
    // stage A: qt[h][m] = sum_d Q[h][d]*Wk[h*4+d][m]
    for (int i = t; i < 4096; i += 1024) {
        int h = i >> 8, m = i & 255;
        float s = 0.f;
        #pragma unroll
        for (int d = 0; d < 4; ++d) s += Q[h*4+d] * Wk[(h*4+d)*256 + m];
        ws[WS_QT + h*256 + m] = s;
    }
    __syncthreads();
    // stage B: wt[h][c] = qt[h]·conv_w[:,c]; u[c][h] = wt*gn_w[c]
    for (int i = t; i < 2048; i += 1024) {
        int h = i >> 7, c = i & 127;
        const float* qt = ws + WS_QT + h*256;
        float s = 0.f;
        #pragma unroll 8
        for (int m = 0; m < 256; ++m) s += qt[m] * conv_w[m*128 + c];
        ws[WS_WT + h*128 + c] = s;
        ws[WS_U  + c*16  + h] = s * gn_w[c];
    }
    __syncthreads();
    // stage C
    __shared__ float red[256];
    __shared__ float sc[16];
    __shared__ float qsv[256];
    __shared__ float rden[16];
    if (t < 256) {
        int h = t >> 4, g = t & 15;
        float s = 0.f;
        #pragma unroll
        for (int cc = 0; cc < 8; ++cc) s += ws[WS_U + (g*8+cc)*16 + h];
        ws[WS_UU + g*16 + h] = s;
        float q = 0.f;
        #pragma unroll
        for (int r = 0; r < 16; ++r) q += ws[WS_QT + h*256 + r*16 + g];
        qsv[h*16 + g] = q;
        // wb partial: thread (h,p=g) covers channels p*8..p*8+7
        float wbp = 0.f;
        #pragma unroll
        for (int i = 0; i < 8; ++i) { int c = g*8+i; wbp += ws[WS_WT + h*128 + c] * gn_b[c]; }
        red[t] = wbp;
    }
    __syncthreads();
    if (t < 16) {
        float wb = 0.f;
        #pragma unroll
        for (int p = 0; p < 16; ++p) wb += red[t*16+p];
        sc[t] = wb;
    }
    __syncthreads();
    if (t < 256) {
        int h = t >> 4, p = t & 15;
        float s = 0.f;
        #pragma unroll
        for (int i = 0; i < 16; ++i) { int m = p*16+i; s += ws[WS_QT + h*256 + m] * conv_b[m]; }
        red[t] = s;
    }
    __syncthreads();
    if (t < 16) {
        float s0 = 0.f;
        #pragma unroll
        for (int p = 0; p < 16; ++p) s0 += red[t*16+p];
        #pragma unroll
        for (int d = 0; d < 4; ++d) s0 += Q[t*4+d] * bk[t*4+d];
        sc[t] += s0;
        rden[t] = powf(1000.0f, -((float)(t >> 1)) * 0.125f);
    }
    if (t < 120) ws[WS_FLAG + t] = pmask[t] ? 1.f : 0.f;
    __syncthreads();
    for (int idx = t; idx < 1920; idx += 1024) {
        int h = idx / 120, r = idx - h*120;     // r = b*30+l
        float pos = (float)bpos[r];
        float pt = 0.f;
        #pragma unroll
        for (int p = 0; p < 16; ++p) {
            float tab = pos * rden[p];
            float v = (p & 1) ? cosf(tab) : sinf(tab);
            pt += v * qsv[h*16 + p];
        }
        ws[WS_P2 + r*16 + h] = pt + sc[h];
    }
}

// ---- k1: GN stats, 2 pixels/thread, float2 loads, direct inv/mui ----
__global__ void __launch_bounds__(256) k1(const float* __restrict__ x,
                                          float* __restrict__ ws) {
    int bx = blockIdx.x;                     // 512 blocks: g = bx>>5
    int g = bx >> 5;
    int pq = (bx & 31)*256 + threadIdx.x;
    int pix0 = pq*2;
    int b = pix0 >> 12, pij = pix0 & 4095;
    const float2* xp = (const float2*)(x + (b*30*128 + g*8)*4096 + pij);
    float sx = 0.f, sy = 0.f, ssx = 0.f, ssy = 0.f;
    for (int l = 0; l < 30; ++l) {
        const float2* xl = xp + l*128*2048;
        #pragma unroll
        for (int c = 0; c < 8; ++c) {
            float2 v = xl[c*2048];
            sx += v.x; sy += v.y;
            ssx += v.x*v.x; ssy += v.y*v.y;
        }
    }
    float mux = sx*(1.f/240.f), muy = sy*(1.f/240.f);
    float ivx = rsqrtf(ssx*(1.f/240.f) - mux*mux + EPSV);
    float ivy = rsqrtf(ssy*(1.f/240.f) - muy*muy + EPSV);
    *(float2*)(ws + WS_INV + g*16384 + pix0) = make_float2(ivx, ivy);
    *(float2*)(ws + WS_MUI + g*16384 + pix0) = make_float2(mux*ivx, muy*ivy);
}

// ---- k2: raw scores, 4 pixels/thread, float4, b128 u-reads, g-loop unroll 1 ----
__global__ void __launch_bounds__(256) k2(const float* __restrict__ x,
                                          const float* __restrict__ ws,
                                          float* __restrict__ out) {
    __shared__ float su[2048];   // u[c][h], h contiguous
    __shared__ float sU[256];    // U[g][h], h contiguous
    __shared__ float sP2[16];
    __shared__ float sflag;
    int t = threadIdx.x;
    int bx = blockIdx.x;                 // 480 blocks: pb2 = bx/30, l = bx%30
    int pb2 = bx / 30, l = bx - pb2*30;
    int pixbase = pb2 * 1024;            // block-uniform
    int b = pixbase >> 12;               // block-uniform
    int pijb = pixbase & 4095;           // block-uniform
    int bl = b*30 + l;                   // block-uniform
    int pij = pijb + t*4;
    int pix0 = pixbase + t*4;

    for (int i = t; i < 512; i += 256)
        *(float4*)(su + i*4) = *(const float4*)(ws + WS_U + i*4);
    sU[t] = ws[WS_UU + t];
    if (t < 16) sP2[t] = ws[WS_P2 + bl*16 + t];
    if (t == 0) sflag = ws[WS_FLAG + bl];
    __syncthreads();

    float4 acc[16];
    #pragma unroll
    for (int h = 0; h < 16; ++h) acc[h] = make_float4(0.f, 0.f, 0.f, 0.f);
    const float* xbase = x + (bl*128)*4096 + pij;
    #pragma unroll 1
    for (int g = 0; g < 16; ++g) {
        float4 inv = *(const float4*)(ws + WS_INV + g*16384 + pix0);
        float4 mui = *(const float4*)(ws + WS_MUI + g*16384 + pix0);
        const float* us = su + g*128;
        #pragma unroll
        for (int q = 0; q < 4; ++q) {
            float4 Ug = *(const float4*)(sU + g*16 + q*4);
            NMA4(acc[q*4+0], Ug.x, mui); NMA4(acc[q*4+1], Ug.y, mui);
            NMA4(acc[q*4+2], Ug.z, mui); NMA4(acc[q*4+3], Ug.w, mui);
        }
        const float* xg = xbase + g*8*4096;
        #pragma unroll
        for (int cc = 0; cc < 8; ++cc) {
            float4 v = *(const float4*)(xg + cc*4096);
            float4 xs;
            xs.x = v.x*inv.x; xs.y = v.y*inv.y; xs.z = v.z*inv.z; xs.w = v.w*inv.w;
            #pragma unroll
            for (int q = 0; q < 4; ++q) {
                float4 uq = *(const float4*)(us + cc*16 + q*4);  // ds_read_b128 broadcast
                FMA4(acc[q*4+0], uq.x, xs); FMA4(acc[q*4+1], uq.y, xs);
                FMA4(acc[q*4+2], uq.z, xs); FMA4(acc[q*4+3], uq.w, xs);
            }
        }
    }
    bool msk = (sflag != 0.f);
    #pragma unroll
    for (int h = 0; h < 16; ++h) {
        float p2 = sP2[h];
        float4 sv;
        sv.x = 0.5f*(acc[h].x + p2); sv.y = 0.5f*(acc[h].y + p2);
        sv.z = 0.5f*(acc[h].z + p2); sv.w = 0.5f*(acc[h].w + p2);
        if (msk) sv = make_float4(-1000.f, -1000.f, -1000.f, -1000.f);
        *(float4*)(out + ((h*4 + b)*30 + l)*4096 + pij) = sv;
    }
}

// ---- k3: softmax over l, 4 pixels/thread ----
__global__ void __launch_bounds__(256) k3(float* __restrict__ out) {
    int idx = blockIdx.x*256 + threadIdx.x;   // 256 blocks, 65536 threads
    int hb = idx >> 10;                       // 64 (h*4+b) slabs
    int pij = (idx & 1023)*4;
    float* p = out + hb*30*4096 + pij;
    float4 v[30];
    float4 m = make_float4(-1e30f, -1e30f, -1e30f, -1e30f);
    #pragma unroll
    for (int l = 0; l < 30; ++l) {
        v[l] = *(const float4*)(p + l*4096);
        m.x = fmaxf(m.x, v[l].x); m.y = fmaxf(m.y, v[l].y);
        m.z = fmaxf(m.z, v[l].z); m.w = fmaxf(m.w, v[l].w);
    }
    float4 s = make_float4(0.f, 0.f, 0.f, 0.f);
    #pragma unroll
    for (int l = 0; l < 30; ++l) {
        v[l].x = __expf(v[l].x - m.x); s.x += v[l].x;
        v[l].y = __expf(v[l].y - m.y); s.y += v[l].y;
        v[l].z = __expf(v[l].z - m.z); s.z += v[l].z;
        v[l].w = __expf(v[l].w - m.w); s.w += v[l].w;
    }
    float4 r; r.x = 1.f/s.x; r.y = 1.f/s.y; r.z = 1.f/s.z; r.w = 1.f/s.w;
    #pragma unroll
    for (int l = 0; l < 30; ++l) {
        float4 o;
        o.x = v[l].x*r.x; o.y = v[l].y*r.y; o.z = v[l].z*r.z; o.w = v[l].w*r.w;
        *(float4*)(p + l*4096) = o;
    }
}

extern "C" void kernel_launch(void* const* d_in, const int* in_sizes, int n_in,
                              void* d_out, int out_size, void* d_ws, size_t ws_size,
                              hipStream_t stream) {
    const float* x      = (const float*)d_in[0];
    const float* gn_w   = (const float*)d_in[1];
    const float* gn_b   = (const float*)d_in[2];
    const float* conv_w = (const float*)d_in[3];
    const float* conv_b = (const float*)d_in[4];
    const float* Q      = (const float*)d_in[5];
    const float* Wk     = (const float*)d_in[6];
    const float* bk     = (const float*)d_in[7];
    const int*   bpos   = (const int*)d_in[8];
    const unsigned char* pmask = (const unsigned char*)d_in[9];
    float* ws  = (float*)d_ws;
    float* out = (float*)d_out;

    hipLaunchKernelGGL(k0, dim3(1),   dim3(1024), 0, stream,
                       Q, Wk, conv_w, gn_w, conv_b, gn_b, bk, bpos, pmask, ws);
    hipLaunchKernelGGL(k1, dim3(512), dim3(256),  0, stream, x, ws);
    hipLaunchKernelGGL(k2, dim3(480), dim3(256),  0, stream, x, ws, out);
    hipLaunchKernelGGL(k3, dim3(256), dim3(256),  0, stream, out);
}